// Round 7
// baseline (197.192 us; speedup 1.0000x reference)
//
#include <hip/hip_runtime.h>
#include <math.h>

// N = 160000 = 256 * 625; four-step FFT decomposition.
// f1: pack w+i*o (float4 loads), per-wave IN-PLACE DIF-625 (barrier-free, sincos),
//     stage-4 scatter to natural order, twiddle, -> G[k2][n1]
// f2: per-wave IN-PLACE DIF-256 (barrier-free), natural-order store -> X[k2][k1]
// i1: sparse band load, inverse 256-FFT (ping-pong; deep block queue hides barriers) -> H
// i2: in-place DIF-625 (sign +), 2 waves/column, fused hop energies; split into 2
//     dispatches for profiler visibility.
constexpr int L      = 160000;
constexpr int BATCH  = 8;
constexpr int NB     = 8;
constexpr int NHOPS  = 156;
constexpr int NCHUNK = 155;
constexpr float TWO_PI = 6.28318530717958647692f;

__device__ __forceinline__ float2 cmulf(float2 a, float2 b) {
  return make_float2(a.x * b.x - a.y * b.y, a.x * b.y + a.y * b.x);
}

template <int SIGN>
__device__ __forceinline__ float2 twld(const float2* __restrict__ W, int idx) {
  float2 t = W[idx];
  if constexpr (SIGN > 0) t.y = -t.y;
  return t;
}

template <int SIGN>
__device__ __forceinline__ void bf4s(float2* v) {
  float2 t0 = make_float2(v[0].x + v[2].x, v[0].y + v[2].y);
  float2 t1 = make_float2(v[0].x - v[2].x, v[0].y - v[2].y);
  float2 t2 = make_float2(v[1].x + v[3].x, v[1].y + v[3].y);
  float2 t3 = make_float2(v[1].x - v[3].x, v[1].y - v[3].y);
  v[0] = make_float2(t0.x + t2.x, t0.y + t2.y);
  v[2] = make_float2(t0.x - t2.x, t0.y - t2.y);
  if constexpr (SIGN < 0) {
    v[1] = make_float2(t1.x + t3.y, t1.y - t3.x);
    v[3] = make_float2(t1.x - t3.y, t1.y + t3.x);
  } else {
    v[1] = make_float2(t1.x - t3.y, t1.y + t3.x);
    v[3] = make_float2(t1.x + t3.y, t1.y - t3.x);
  }
}

template <int SIGN>
__device__ __forceinline__ void bf5s(float2* v) {
  const float c1 = 0.30901699437494745f, s1 = 0.9510565162951535f;
  const float c2 = -0.8090169943749475f, s2 = 0.5877852522924731f;
  float2 t1 = make_float2(v[1].x + v[4].x, v[1].y + v[4].y);
  float2 t3 = make_float2(v[1].x - v[4].x, v[1].y - v[4].y);
  float2 t2 = make_float2(v[2].x + v[3].x, v[2].y + v[3].y);
  float2 t4 = make_float2(v[2].x - v[3].x, v[2].y - v[3].y);
  float2 a = make_float2(v[0].x + c1 * t1.x + c2 * t2.x, v[0].y + c1 * t1.y + c2 * t2.y);
  float2 b = make_float2(s1 * t3.x + s2 * t4.x, s1 * t3.y + s2 * t4.y);
  float2 c = make_float2(v[0].x + c2 * t1.x + c1 * t2.x, v[0].y + c2 * t1.y + c1 * t2.y);
  float2 d = make_float2(s2 * t3.x - s1 * t4.x, s2 * t3.y - s1 * t4.y);
  v[0] = make_float2(v[0].x + t1.x + t2.x, v[0].y + t1.y + t2.y);
  if constexpr (SIGN < 0) {
    v[1] = make_float2(a.x + b.y, a.y - b.x);
    v[4] = make_float2(a.x - b.y, a.y + b.x);
    v[2] = make_float2(c.x + d.y, c.y - d.x);
    v[3] = make_float2(c.x - d.y, c.y + d.x);
  } else {
    v[1] = make_float2(a.x - b.y, a.y + b.x);
    v[4] = make_float2(a.x + b.y, a.y - b.x);
    v[2] = make_float2(c.x - d.y, c.y + d.x);
    v[3] = make_float2(c.x + d.y, c.y - d.x);
  }
}

template <int R>
__device__ __forceinline__ void twchain(float2* v, float2 t1) {
  float2 t = t1;
  v[1] = cmulf(v[1], t);
#pragma unroll
  for (int r = 2; r < R; ++r) { t = cmulf(t, t1); v[r] = cmulf(v[r], t); }
}

__device__ __forceinline__ int rev3_5(int q) {  // reverse 3 base-5 digits, q<125
  int q5 = q / 5, q25 = q / 25;
  int d0 = q - 5 * q5, d1 = q5 - 5 * q25;
  return 25 * d0 + 5 * d1 + q25;
}

__device__ __forceinline__ int rev3_4(int q) {  // reverse 3 base-4 digits, q<64
  return ((q & 3) << 4) | (q & 12) | (q >> 4);
}

// ---------- in-place DIF-625 (per-wave private, barrier-free, sincos twiddles) ----------
// Batched: all reads of both butterflies before any write (WAR-safe, per-wave DS in-order).
template <int SUB, int SIGN>
__device__ __forceinline__ void dif5_ip_stage(float2* a, int ln) {
  int i1 = ln, i2 = ln + 64;
  bool g2 = (i2 < 125);
  int j1 = i1 % SUB, j2 = i2 % SUB;
  int b1 = (i1 / SUB) * (5 * SUB) + j1;
  int b2 = (i2 / SUB) * (5 * SUB) + j2;
  float2 u[5], v[5];
#pragma unroll
  for (int r = 0; r < 5; ++r) u[r] = a[b1 + SUB * r];
  if (g2) {
#pragma unroll
    for (int r = 0; r < 5; ++r) v[r] = a[b2 + SUB * r];
  }
  bf5s<SIGN>(u);
  {
    float s, c;
    __sincosf((float)SIGN * (TWO_PI / (float)(5 * SUB)) * (float)j1, &s, &c);
    twchain<5>(u, make_float2(c, s));
  }
  if (g2) {
    bf5s<SIGN>(v);
    float s, c;
    __sincosf((float)SIGN * (TWO_PI / (float)(5 * SUB)) * (float)j2, &s, &c);
    twchain<5>(v, make_float2(c, s));
  }
#pragma unroll
  for (int r = 0; r < 5; ++r) a[b1 + SUB * r] = u[r];
  if (g2) {
#pragma unroll
    for (int r = 0; r < 5; ++r) a[b2 + SUB * r] = v[r];
  }
}

template <int SIGN>
__device__ __forceinline__ void dif625_ip(float2* a, int ln) {
  dif5_ip_stage<125, SIGN>(a, ln);
  dif5_ip_stage<25, SIGN>(a, ln);
  dif5_ip_stage<5, SIGN>(a, ln);
  // last stage: read a[5q+r], butterfly, scatter to NATURAL order k = 125 r + rev3_5(q)
  int q1 = ln, q2 = ln + 64;
  bool g2 = (q2 < 125);
  float2 u[5], v[5];
#pragma unroll
  for (int r = 0; r < 5; ++r) u[r] = a[5 * q1 + r];
  if (g2) {
#pragma unroll
    for (int r = 0; r < 5; ++r) v[r] = a[5 * q2 + r];
  }
  bf5s<SIGN>(u);
  if (g2) bf5s<SIGN>(v);
  int rv1 = rev3_5(q1), rv2 = rev3_5(q2);
#pragma unroll
  for (int r = 0; r < 5; ++r) a[125 * r + rv1] = u[r];
  if (g2) {
#pragma unroll
    for (int r = 0; r < 5; ++r) a[125 * r + rv2] = v[r];
  }
}

// ---------- in-place DIF-256 (per-wave private, barrier-free; 1 butterfly/lane/stage) ----------
template <int SIGN>
__device__ __forceinline__ void dif256_ip(float2* a, int ln) {
  {  // stage 1: b = ln, stride 64, tw W256^{ln r}
    float2 u[4];
#pragma unroll
    for (int r = 0; r < 4; ++r) u[r] = a[ln + 64 * r];
    bf4s<SIGN>(u);
    float s, c;
    __sincosf((float)SIGN * (TWO_PI / 256.0f) * (float)ln, &s, &c);
    twchain<4>(u, make_float2(c, s));
#pragma unroll
    for (int r = 0; r < 4; ++r) a[ln + 64 * r] = u[r];
  }
  {  // stage 2: b = 64*(ln>>4) + (ln&15), stride 16, tw W64^{j r}
    int j = ln & 15, b = 64 * (ln >> 4) + j;
    float2 u[4];
#pragma unroll
    for (int r = 0; r < 4; ++r) u[r] = a[b + 16 * r];
    bf4s<SIGN>(u);
    float s, c;
    __sincosf((float)SIGN * (TWO_PI / 64.0f) * (float)j, &s, &c);
    twchain<4>(u, make_float2(c, s));
#pragma unroll
    for (int r = 0; r < 4; ++r) a[b + 16 * r] = u[r];
  }
  {  // stage 3: b = 16*(ln>>2) + (ln&3), stride 4, tw W16^{j r}
    int j = ln & 3, b = 16 * (ln >> 2) + j;
    float2 u[4];
#pragma unroll
    for (int r = 0; r < 4; ++r) u[r] = a[b + 4 * r];
    bf4s<SIGN>(u);
    float s, c;
    __sincosf((float)SIGN * (TWO_PI / 16.0f) * (float)j, &s, &c);
    twchain<4>(u, make_float2(c, s));
#pragma unroll
    for (int r = 0; r < 4; ++r) a[b + 4 * r] = u[r];
  }
  {  // stage 4: read a[4 ln + r], butterfly, scatter NATURAL k1 = 64 r + rev3_4(ln)
    float2 u[4];
#pragma unroll
    for (int r = 0; r < 4; ++r) u[r] = a[4 * ln + r];
    bf4s<SIGN>(u);
    int rv = rev3_4(ln);
#pragma unroll
    for (int r = 0; r < 4; ++r) a[64 * r + rv] = u[r];
  }
}

// ---------- R2-style Stockham stage (kept for i1: deep block queue hides barriers) ----------
template <int R, int Ns, int SIGN, int M>
__device__ __forceinline__ void lds_stage_sc(const float2* in, float2* out, int w) {
  constexpr int NR = M / R;
  for (int j = w; j < NR; j += 64) {
    float2 v[R];
#pragma unroll
    for (int r = 0; r < R; ++r) v[r] = in[j + r * NR];
    int jm = j % Ns;
    float base = (float)SIGN * (TWO_PI / (float)(Ns * R)) * (float)jm;
#pragma unroll
    for (int r = 1; r < R; ++r) {
      float s, c;
      __sincosf((float)r * base, &s, &c);
      v[r] = cmulf(v[r], make_float2(c, s));
    }
    if constexpr (R == 4) bf4s<SIGN>(v); else bf5s<SIGN>(v);
    int od = (j / Ns) * (Ns * R) + jm;
#pragma unroll
    for (int r = 0; r < R; ++r) out[od + r * Ns] = v[r];
  }
}

template <int SIGN>
__device__ __forceinline__ void fft256_sc(float2* a, float2* b, int w) {
  lds_stage_sc<4, 1, SIGN, 256>(a, b, w);   __syncthreads();
  lds_stage_sc<4, 4, SIGN, 256>(b, a, w);   __syncthreads();
  lds_stage_sc<4, 16, SIGN, 256>(a, b, w);  __syncthreads();
  lds_stage_sc<4, 64, SIGN, 256>(b, a, w);  __syncthreads();  // result in a
}

// ---------- setup: W[k] = e^{-2pi i k/L} (used by i2 only) ----------
__global__ __launch_bounds__(256) void setup_kernel(float2* __restrict__ W) {
  int k = blockIdx.x * 256 + threadIdx.x;
  if (k < L) {
    float s, c;
    sincosf(-TWO_PI * ((float)k / (float)L), &s, &c);
    W[k] = make_float2(c, s);
  }
}

// ---------- F1: float4 pack, per-wave in-place DIF-625, twiddle, store [k2][n1] ----------
__global__ __launch_bounds__(256) void f1_kernel(const float* __restrict__ win,
                                                 const float* __restrict__ oin,
                                                 float2* __restrict__ G) {
  __shared__ float2 A[4 * 625];    // 20 KB, in-place (no ping-pong)
  int blk = blockIdx.x;
  int sig = blk >> 6, g = blk & 63;
  int n1base = g * 4;
  int tid = threadIdx.x;
  const float4* wp4 = (const float4*)(win + (size_t)sig * L);
  const float4* op4 = (const float4*)(oin + (size_t)sig * L);
  for (int r = tid; r < 625; r += 256) {
    float4 wv = wp4[r * 64 + g];
    float4 ov = op4[r * 64 + g];
    A[0 * 625 + r] = make_float2(wv.x, ov.x);
    A[1 * 625 + r] = make_float2(wv.y, ov.y);
    A[2 * 625 + r] = make_float2(wv.z, ov.z);
    A[3 * 625 + r] = make_float2(wv.w, ov.w);
  }
  __syncthreads();
  int wv_ = tid >> 6, ln = tid & 63;
  dif625_ip<-1>(A + wv_ * 625, ln);   // barrier-free, per-wave column; natural order out
  __syncthreads();
  for (int idx = tid; idx < 2500; idx += 256) {
    int k2 = idx >> 2, cc = idx & 3;
    int n1 = n1base + cc;
    float ang = -(TWO_PI / (float)L) * (float)(n1 * k2);
    float s, c;
    __sincosf(ang, &s, &c);
    G[(size_t)sig * L + k2 * 256 + n1] = cmulf(A[cc * 625 + k2], make_float2(c, s));
  }
}

// ---------- F2: per-wave in-place DIF-256 (own-row load, 1 barrier), -> X[k2][k1] ----------
__global__ __launch_bounds__(256) void f2_kernel(const float2* __restrict__ G,
                                                 float2* __restrict__ X) {
  __shared__ float2 A[4 * 257];    // 8.2 KB
  int blk = blockIdx.x;
  int sig = blk / 157, gr = blk % 157;
  int k2base = gr * 4;
  int tid = threadIdx.x;
  int wv = tid >> 6, ln = tid & 63;
  int k2 = k2base + wv;
  float2* a = A + wv * 257;
  if (k2 < 625) {
#pragma unroll
    for (int r = 0; r < 4; ++r) a[ln + 64 * r] = G[(size_t)sig * L + k2 * 256 + ln + 64 * r];
    dif256_ip<-1>(a, ln);           // barrier-free, per-wave row; natural order out
  }
  __syncthreads();
  for (int idx = tid; idx < 1024; idx += 256) {
    int row = idx >> 8, k1 = idx & 255;
    int k2e = k2base + row;
    if (k2e < 625) X[(size_t)sig * L + k2e * 256 + k1] = A[row * 257 + k1];
  }
}

// ---------- I1: sparse band load, inverse 256-FFT over k1 (ping-pong), -> H[n1][k2] ----------
__global__ __launch_bounds__(256) void i1_kernel(const float2* __restrict__ X,
                                                 float2* __restrict__ H) {
  __shared__ float2 A[4 * 257], B[4 * 257];
  int blk = blockIdx.x;
  int gr = blk % 157, sb = blk / 157;
  int band = sb & 7, sig = sb >> 3;
  int k2base = gr * 4;
  int tid = threadIdx.x;
  int wv = tid >> 6, ln = tid & 63;
  int k2 = k2base + wv;
  {
    float2* row = A + wv * 257;
    float2 zero = make_float2(0.0f, 0.0f);
    for (int k1 = ln; k1 < 256; k1 += 64) row[k1] = zero;   // same wave: DS in-order
    if (k2 < 625) {
      int lo1, hi1, lo2, hi2;
      if (band < 7) {
        lo1 = 10000 * band + 1;        hi1 = 10000 * (band + 1);
        lo2 = L - 10000 * (band + 1);  hi2 = L - 10000 * band - 1;
      } else {
        lo1 = 70001; hi1 = 80000; lo2 = 80001; hi2 = 89999;
      }
      const float2* Xr = X + (size_t)sig * L + k2 * 256;
      int s1 = (lo1 - k2 + 624) / 625;
      int e1 = (hi1 - k2) / 625; if (e1 > 255) e1 = 255;
      int s2 = (lo2 - k2 + 624) / 625;
      int e2 = (hi2 - k2) / 625; if (e2 > 255) e2 = 255;
      int c1 = e1 - s1 + 1;
      int c2 = e2 - s2 + 1;
      if (ln < c1) { int k1 = s1 + ln; row[k1] = Xr[k1]; }
      int l2 = ln - 32;
      if (l2 >= 0 && l2 < c2) { int k1 = s2 + l2; row[k1] = Xr[k1]; }
      if (band == 7 && k2 == 0 && ln == 0) row[0] = Xr[0];   // DC bin -> band 7
    }
  }
  __syncthreads();
  fft256_sc<1>(A + wv * 257, B + wv * 257, ln);
  size_t obase = (size_t)(sig * NB + band) * L;
  for (int idx = tid; idx < 1024; idx += 256) {
    int cc = idx & 3, n1 = idx >> 2;
    int k2e = k2base + cc;
    if (k2e < 625) {
      float ang = (TWO_PI / (float)L) * (float)(n1 * k2e);
      float s, c;
      __sincosf(ang, &s, &c);
      H[obase + (size_t)n1 * 625 + k2e] = cmulf(A[cc * 257 + n1], make_float2(c, s));
    }
  }
}

// ---------- I2: in-place DIF-625 (sign +), 2 waves per column, fused hop energies ----------
// sig0 splits the launch into halves (profiler visibility; perf-neutral).
__global__ __launch_bounds__(512) void i2_kernel(const float2* __restrict__ H,
                                                 float* __restrict__ E,
                                                 const float2* __restrict__ W,
                                                 int sig0) {
  __shared__ float2 A[4 * 625];      // 20000 B
  __shared__ float P[2 * NHOPS];     // 1248 B
  int blk = blockIdx.x;
  int g = blk & 63, sb = blk >> 6;
  int band = sb & 7, sig = (sb >> 3) + sig0;
  int tid = threadIdx.x;
  int col = tid >> 7;                 // 4 columns, 2 waves (128 threads) each
  int j = tid & 127;                  // butterfly index within column, <125 active
  bool act = (j < 125);
  for (int idx = tid; idx < 2 * NHOPS; idx += 512) P[idx] = 0.0f;
  int n1 = 4 * g + col;
  const float2* Hc = H + (size_t)(sig * NB + band) * L + (size_t)n1 * 625;
  float2* a = A + col * 625;

  if (act) {  // stage 1: global -> LDS (stride 125, tw W625^{j r} step 256)
    float2 u[5];
#pragma unroll
    for (int r = 0; r < 5; ++r) u[r] = Hc[j + 125 * r];
    bf5s<1>(u);
    twchain<5>(u, twld<1>(W, j * 256));
#pragma unroll
    for (int r = 0; r < 5; ++r) a[j + 125 * r] = u[r];
  }
  __syncthreads();
  if (act) {  // stage 2: stride 25, tw W125^{(j%25) r} step 1280
    int b1 = (j / 25) * 125 + (j % 25);
    float2 u[5];
#pragma unroll
    for (int r = 0; r < 5; ++r) u[r] = a[b1 + 25 * r];
    bf5s<1>(u);
    twchain<5>(u, twld<1>(W, (j % 25) * 1280));
#pragma unroll
    for (int r = 0; r < 5; ++r) a[b1 + 25 * r] = u[r];
  }
  __syncthreads();
  if (act) {  // stage 3: stride 5, tw W25^{(j%5) r} step 6400
    int b1 = (j / 5) * 25 + (j % 5);
    float2 u[5];
#pragma unroll
    for (int r = 0; r < 5; ++r) u[r] = a[b1 + 5 * r];
    bf5s<1>(u);
    twchain<5>(u, twld<1>(W, (j % 5) * 6400));
#pragma unroll
    for (int r = 0; r < 5; ++r) a[b1 + 5 * r] = u[r];
  }
  __syncthreads();
  if (act) {  // stage 4: no twiddle, scatter to NATURAL order n2 = 125 r + rev3(j)
    float2 u[5];
#pragma unroll
    for (int r = 0; r < 5; ++r) u[r] = a[5 * j + r];
    bf5s<1>(u);
    int rv = rev3_5(j);
#pragma unroll
    for (int r = 0; r < 5; ++r) a[125 * r + rv] = u[r];
  }
  __syncthreads();
  // energy: a[n2] = L*(w_band + i*o_band) at n = 256*n2 + n1; hop h sums n2 in [4h,4h+4)
  for (int t = tid; t < 4 * NHOPS; t += 512) {
    int c = t / NHOPS, h = t - c * NHOPS;
    const float2* S = A + c * 625 + 4 * h;
    float ex = 0.0f, ey = 0.0f;
#pragma unroll
    for (int d = 0; d < 4; ++d) {
      float2 z = S[d];
      ex += z.x * z.x;
      ey += z.y * z.y;
    }
    atomicAdd(&P[h], ex);
    atomicAdd(&P[NHOPS + h], ey);
  }
  __syncthreads();
  int eb = (sig * NB + band) * NHOPS;
  for (int idx = tid; idx < 2 * NHOPS; idx += 512) {
    int comp = idx / NHOPS, h = idx - comp * NHOPS;
    atomicAdd(&E[comp * (BATCH * NB * NHOPS) + eb + h], P[idx]);
  }
}

// ---------- finalize: loudness, diff, softmax-weighted sum (1/L^2 folded into SC) ----------
__global__ __launch_bounds__(1024) void finalize_kernel(const float* __restrict__ E,
                                                        float* __restrict__ out) {
  constexpr int ND = BATCH * NB * NCHUNK;  // 9920
  constexpr float SC = (1.0f / 2048.0f) / ((float)L * (float)L);
  __shared__ float diffs[ND];
  __shared__ float sred[1024];
  int tid = threadIdx.x;
  for (int idx = tid; idx < ND; idx += 1024) {
    int sb = idx / NCHUNK;
    int k = idx - sb * NCHUNK;
    float msw = (E[sb * NHOPS + k] + E[sb * NHOPS + k + 1]) * SC;
    float mso = (E[64 * NHOPS + sb * NHOPS + k] + E[64 * NHOPS + sb * NHOPS + k + 1]) * SC;
    float lw = -0.691f + 10.0f * log10f(msw + 1e-12f);
    float lo = -0.691f + 10.0f * log10f(mso + 1e-12f);
    diffs[idx] = lw - lo;
  }
  __syncthreads();
  float mx = -3.4e38f;
  for (int idx = tid; idx < ND; idx += 1024) mx = fmaxf(mx, diffs[idx]);
  sred[tid] = mx;
  __syncthreads();
  for (int s = 512; s > 0; s >>= 1) {
    if (tid < s) sred[tid] = fmaxf(sred[tid], sred[tid + s]);
    __syncthreads();
  }
  float gmax = sred[0];
  __syncthreads();
  float se = 0.0f, swd = 0.0f;
  for (int idx = tid; idx < ND; idx += 1024) {
    float d = diffs[idx];
    float e = expf(d - gmax);
    se += e;
    swd += d * e;
  }
  sred[tid] = se; __syncthreads();
  for (int s = 512; s > 0; s >>= 1) { if (tid < s) sred[tid] += sred[tid + s]; __syncthreads(); }
  float tot = sred[0];
  __syncthreads();
  sred[tid] = swd; __syncthreads();
  for (int s = 512; s > 0; s >>= 1) { if (tid < s) sred[tid] += sred[tid + s]; __syncthreads(); }
  if (tid == 0) out[0] = sred[0] / tot;
}

extern "C" void kernel_launch(void* const* d_in, const int* in_sizes, int n_in,
                              void* d_out, int out_size, void* d_ws, size_t ws_size,
                              hipStream_t stream) {
  (void)in_sizes; (void)n_in; (void)out_size; (void)ws_size;
  char* ws = (char*)d_ws;
  float2* G = (float2*)ws;                        // 10,240,000 B
  float2* X = (float2*)(ws + 10240000);           // 10,240,000 B
  float2* H = (float2*)(ws + 20480000);           // 81,920,000 B
  float*  E = (float*)(ws + 102400000);           // 79,872 B [2][64][156]
  float2* W = (float2*)(ws + 102480000);          // 1,280,000 B twiddles (i2 only)
  const float* w = (const float*)d_in[0];
  const float* o = (const float*)d_in[1];

  setup_kernel<<<dim3(625), dim3(256), 0, stream>>>(W);
  f1_kernel<<<dim3(BATCH * 64), dim3(256), 0, stream>>>(w, o, G);
  f2_kernel<<<dim3(BATCH * 157), dim3(256), 0, stream>>>(G, X);
  i1_kernel<<<dim3(BATCH * NB * 157), dim3(256), 0, stream>>>(X, H);
  hipMemsetAsync(E, 0, 2 * BATCH * NB * NHOPS * sizeof(float), stream);
  i2_kernel<<<dim3(4 * NB * 64), dim3(512), 0, stream>>>(H, E, W, 0);
  i2_kernel<<<dim3(4 * NB * 64), dim3(512), 0, stream>>>(H, E, W, 4);
  finalize_kernel<<<dim3(1), dim3(1024), 0, stream>>>(E, (float*)d_out);
}

// Round 8
// 180.781 us; speedup vs baseline: 1.0908x; 1.0908x over previous
//
#include <hip/hip_runtime.h>
#include <math.h>

// N = 160000 = 256 * 625; four-step FFT decomposition.
// f1: pack w+i*o (float4), per-wave in-place DIF-625 (barrier-free), twiddle -> G[k2][n1]
// f2: per-wave in-place DIF-256 (barrier-free) -> X[k2][k1], bin = 625*k1 + k2
// i1: sparse band load, per-wave in-place inverse DIF-256 (4 rows/wave, barrier-free),
//     16 k2 per block -> 128-B coalesced H[n1][k2] writes
// i2: in-place DIF-625 (sign +), 2 waves/column, per-r sincosf twiddles (no table),
//     fused hop energies; split into 2 dispatches for profiler visibility.
// All twiddles: per-r __sincosf (unchained -> no compounded error; R2 absmax was 0.0).
constexpr int L      = 160000;
constexpr int BATCH  = 8;
constexpr int NB     = 8;
constexpr int NHOPS  = 156;
constexpr int NCHUNK = 155;
constexpr float TWO_PI = 6.28318530717958647692f;

__device__ __forceinline__ float2 cmulf(float2 a, float2 b) {
  return make_float2(a.x * b.x - a.y * b.y, a.x * b.y + a.y * b.x);
}

template <int SIGN>
__device__ __forceinline__ void bf4s(float2* v) {
  float2 t0 = make_float2(v[0].x + v[2].x, v[0].y + v[2].y);
  float2 t1 = make_float2(v[0].x - v[2].x, v[0].y - v[2].y);
  float2 t2 = make_float2(v[1].x + v[3].x, v[1].y + v[3].y);
  float2 t3 = make_float2(v[1].x - v[3].x, v[1].y - v[3].y);
  v[0] = make_float2(t0.x + t2.x, t0.y + t2.y);
  v[2] = make_float2(t0.x - t2.x, t0.y - t2.y);
  if constexpr (SIGN < 0) {
    v[1] = make_float2(t1.x + t3.y, t1.y - t3.x);
    v[3] = make_float2(t1.x - t3.y, t1.y + t3.x);
  } else {
    v[1] = make_float2(t1.x - t3.y, t1.y + t3.x);
    v[3] = make_float2(t1.x + t3.y, t1.y - t3.x);
  }
}

template <int SIGN>
__device__ __forceinline__ void bf5s(float2* v) {
  const float c1 = 0.30901699437494745f, s1 = 0.9510565162951535f;
  const float c2 = -0.8090169943749475f, s2 = 0.5877852522924731f;
  float2 t1 = make_float2(v[1].x + v[4].x, v[1].y + v[4].y);
  float2 t3 = make_float2(v[1].x - v[4].x, v[1].y - v[4].y);
  float2 t2 = make_float2(v[2].x + v[3].x, v[2].y + v[3].y);
  float2 t4 = make_float2(v[2].x - v[3].x, v[2].y - v[3].y);
  float2 a = make_float2(v[0].x + c1 * t1.x + c2 * t2.x, v[0].y + c1 * t1.y + c2 * t2.y);
  float2 b = make_float2(s1 * t3.x + s2 * t4.x, s1 * t3.y + s2 * t4.y);
  float2 c = make_float2(v[0].x + c2 * t1.x + c1 * t2.x, v[0].y + c2 * t1.y + c1 * t2.y);
  float2 d = make_float2(s2 * t3.x - s1 * t4.x, s2 * t3.y - s1 * t4.y);
  v[0] = make_float2(v[0].x + t1.x + t2.x, v[0].y + t1.y + t2.y);
  if constexpr (SIGN < 0) {
    v[1] = make_float2(a.x + b.y, a.y - b.x);
    v[4] = make_float2(a.x - b.y, a.y + b.x);
    v[2] = make_float2(c.x + d.y, c.y - d.x);
    v[3] = make_float2(c.x - d.y, c.y + d.x);
  } else {
    v[1] = make_float2(a.x - b.y, a.y + b.x);
    v[4] = make_float2(a.x + b.y, a.y - b.x);
    v[2] = make_float2(c.x - d.y, c.y + d.x);
    v[3] = make_float2(c.x + d.y, c.y - d.x);
  }
}

// per-r twiddle application: v[r] *= e^{i * r * ang}  (unchained -> minimal error)
template <int R>
__device__ __forceinline__ void twapply(float2* v, float ang) {
#pragma unroll
  for (int r = 1; r < R; ++r) {
    float s, c;
    __sincosf(ang * (float)r, &s, &c);
    v[r] = cmulf(v[r], make_float2(c, s));
  }
}

__device__ __forceinline__ int rev3_5(int q) {  // reverse 3 base-5 digits, q<125
  int q5 = q / 5, q25 = q / 25;
  int d0 = q - 5 * q5, d1 = q5 - 5 * q25;
  return 25 * d0 + 5 * d1 + q25;
}

__device__ __forceinline__ int rev3_4(int q) {  // reverse 3 base-4 digits, q<64
  return ((q & 3) << 4) | (q & 12) | (q >> 4);
}

// ---------- in-place DIF-625 (per-wave private, barrier-free, per-r sincos) ----------
template <int SUB, int SIGN>
__device__ __forceinline__ void dif5_ip_stage(float2* a, int ln) {
  int i1 = ln, i2 = ln + 64;
  bool g2 = (i2 < 125);
  int j1 = i1 % SUB, j2 = i2 % SUB;
  int b1 = (i1 / SUB) * (5 * SUB) + j1;
  int b2 = (i2 / SUB) * (5 * SUB) + j2;
  float2 u[5], v[5];
#pragma unroll
  for (int r = 0; r < 5; ++r) u[r] = a[b1 + SUB * r];
  if (g2) {
#pragma unroll
    for (int r = 0; r < 5; ++r) v[r] = a[b2 + SUB * r];
  }
  bf5s<SIGN>(u);
  twapply<5>(u, (float)SIGN * (TWO_PI / (float)(5 * SUB)) * (float)j1);
  if (g2) {
    bf5s<SIGN>(v);
    twapply<5>(v, (float)SIGN * (TWO_PI / (float)(5 * SUB)) * (float)j2);
  }
#pragma unroll
  for (int r = 0; r < 5; ++r) a[b1 + SUB * r] = u[r];
  if (g2) {
#pragma unroll
    for (int r = 0; r < 5; ++r) a[b2 + SUB * r] = v[r];
  }
}

template <int SIGN>
__device__ __forceinline__ void dif625_ip(float2* a, int ln) {
  dif5_ip_stage<125, SIGN>(a, ln);
  dif5_ip_stage<25, SIGN>(a, ln);
  dif5_ip_stage<5, SIGN>(a, ln);
  // last stage: read a[5q+r], butterfly, scatter NATURAL k = 125 r + rev3_5(q)
  int q1 = ln, q2 = ln + 64;
  bool g2 = (q2 < 125);
  float2 u[5], v[5];
#pragma unroll
  for (int r = 0; r < 5; ++r) u[r] = a[5 * q1 + r];
  if (g2) {
#pragma unroll
    for (int r = 0; r < 5; ++r) v[r] = a[5 * q2 + r];
  }
  bf5s<SIGN>(u);
  if (g2) bf5s<SIGN>(v);
  int rv1 = rev3_5(q1), rv2 = rev3_5(q2);
#pragma unroll
  for (int r = 0; r < 5; ++r) a[125 * r + rv1] = u[r];
  if (g2) {
#pragma unroll
    for (int r = 0; r < 5; ++r) a[125 * r + rv2] = v[r];
  }
}

// ---------- in-place DIF-256 (per-wave private, barrier-free; per-r sincos) ----------
template <int SIGN>
__device__ __forceinline__ void dif256_ip(float2* a, int ln) {
  {  // stage 1: b = ln, stride 64, tw W256^{ln r}
    float2 u[4];
#pragma unroll
    for (int r = 0; r < 4; ++r) u[r] = a[ln + 64 * r];
    bf4s<SIGN>(u);
    twapply<4>(u, (float)SIGN * (TWO_PI / 256.0f) * (float)ln);
#pragma unroll
    for (int r = 0; r < 4; ++r) a[ln + 64 * r] = u[r];
  }
  {  // stage 2: stride 16, tw W64^{j r}
    int j = ln & 15, b = 64 * (ln >> 4) + j;
    float2 u[4];
#pragma unroll
    for (int r = 0; r < 4; ++r) u[r] = a[b + 16 * r];
    bf4s<SIGN>(u);
    twapply<4>(u, (float)SIGN * (TWO_PI / 64.0f) * (float)j);
#pragma unroll
    for (int r = 0; r < 4; ++r) a[b + 16 * r] = u[r];
  }
  {  // stage 3: stride 4, tw W16^{j r}
    int j = ln & 3, b = 16 * (ln >> 2) + j;
    float2 u[4];
#pragma unroll
    for (int r = 0; r < 4; ++r) u[r] = a[b + 4 * r];
    bf4s<SIGN>(u);
    twapply<4>(u, (float)SIGN * (TWO_PI / 16.0f) * (float)j);
#pragma unroll
    for (int r = 0; r < 4; ++r) a[b + 4 * r] = u[r];
  }
  {  // stage 4: read a[4 ln + r], butterfly, scatter NATURAL k1 = 64 r + rev3_4(ln)
    float2 u[4];
#pragma unroll
    for (int r = 0; r < 4; ++r) u[r] = a[4 * ln + r];
    bf4s<SIGN>(u);
    int rv = rev3_4(ln);
#pragma unroll
    for (int r = 0; r < 4; ++r) a[64 * r + rv] = u[r];
  }
}

// ---------- F1: float4 pack, per-wave in-place DIF-625, twiddle, store [k2][n1] ----------
__global__ __launch_bounds__(256) void f1_kernel(const float* __restrict__ win,
                                                 const float* __restrict__ oin,
                                                 float2* __restrict__ G) {
  __shared__ float2 A[4 * 625];    // 20 KB, in-place
  int blk = blockIdx.x;
  int sig = blk >> 6, g = blk & 63;
  int n1base = g * 4;
  int tid = threadIdx.x;
  const float4* wp4 = (const float4*)(win + (size_t)sig * L);
  const float4* op4 = (const float4*)(oin + (size_t)sig * L);
  for (int r = tid; r < 625; r += 256) {
    float4 wv = wp4[r * 64 + g];
    float4 ov = op4[r * 64 + g];
    A[0 * 625 + r] = make_float2(wv.x, ov.x);
    A[1 * 625 + r] = make_float2(wv.y, ov.y);
    A[2 * 625 + r] = make_float2(wv.z, ov.z);
    A[3 * 625 + r] = make_float2(wv.w, ov.w);
  }
  __syncthreads();
  int wv_ = tid >> 6, ln = tid & 63;
  dif625_ip<-1>(A + wv_ * 625, ln);   // barrier-free; natural order out
  __syncthreads();
  for (int idx = tid; idx < 2500; idx += 256) {
    int k2 = idx >> 2, cc = idx & 3;
    int n1 = n1base + cc;
    float ang = -(TWO_PI / (float)L) * (float)(n1 * k2);
    float s, c;
    __sincosf(ang, &s, &c);
    G[(size_t)sig * L + k2 * 256 + n1] = cmulf(A[cc * 625 + k2], make_float2(c, s));
  }
}

// ---------- F2: per-wave in-place DIF-256 (1 barrier), -> X[k2][k1] ----------
__global__ __launch_bounds__(256) void f2_kernel(const float2* __restrict__ G,
                                                 float2* __restrict__ X) {
  __shared__ float2 A[4 * 257];
  int blk = blockIdx.x;
  int sig = blk / 157, gr = blk % 157;
  int k2base = gr * 4;
  int tid = threadIdx.x;
  int wv = tid >> 6, ln = tid & 63;
  int k2 = k2base + wv;
  float2* a = A + wv * 257;
  if (k2 < 625) {
#pragma unroll
    for (int r = 0; r < 4; ++r) a[ln + 64 * r] = G[(size_t)sig * L + k2 * 256 + ln + 64 * r];
    dif256_ip<-1>(a, ln);
  }
  __syncthreads();
  for (int idx = tid; idx < 1024; idx += 256) {
    int row = idx >> 8, k1 = idx & 255;
    int k2e = k2base + row;
    if (k2e < 625) X[(size_t)sig * L + k2e * 256 + k1] = A[row * 257 + k1];
  }
}

// ---------- I1: sparse band load, per-wave inverse DIF-256 x4 rows, 16 k2/block ----------
// Epilogue writes 16 consecutive k2 per n1 -> 128-B full-line H writes (kills the
// 1.7x write amplification seen in R7: WRITE_SIZE 140 MB for an 82 MB H).
__global__ __launch_bounds__(256) void i1_kernel(const float2* __restrict__ X,
                                                 float2* __restrict__ H) {
  __shared__ float2 A[16 * 257];   // 32,896 B -> 4 blocks/CU, barrier-free waves
  int blk = blockIdx.x;
  int gr = blk % 40, sb = blk / 40;
  int band = sb & 7, sig = sb >> 3;
  int k2base = gr * 16;
  int tid = threadIdx.x;
  int wv = tid >> 6, ln = tid & 63;
  int lo1, hi1, lo2, hi2;
  if (band < 7) {
    lo1 = 10000 * band + 1;        hi1 = 10000 * (band + 1);
    lo2 = L - 10000 * (band + 1);  hi2 = L - 10000 * band - 1;
  } else {
    lo1 = 70001; hi1 = 80000; lo2 = 80001; hi2 = 89999;
  }
  float2 zero = make_float2(0.0f, 0.0f);
#pragma unroll
  for (int i = 0; i < 4; ++i) {
    int lr = wv * 4 + i;
    int k2 = k2base + lr;
    float2* row = A + lr * 257;
    for (int k1 = ln; k1 < 256; k1 += 64) row[k1] = zero;   // same wave: DS in-order
    if (k2 < 625) {
      const float2* Xr = X + (size_t)sig * L + k2 * 256;
      int s1 = (lo1 - k2 + 624) / 625;
      int e1 = (hi1 - k2) / 625; if (e1 > 255) e1 = 255;
      int s2 = (lo2 - k2 + 624) / 625;
      int e2 = (hi2 - k2) / 625; if (e2 > 255) e2 = 255;
      int c1 = e1 - s1 + 1;
      int c2 = e2 - s2 + 1;
      if (ln < c1) { int k1 = s1 + ln; row[k1] = Xr[k1]; }
      int l2 = ln - 32;
      if (l2 >= 0 && l2 < c2) { int k1 = s2 + l2; row[k1] = Xr[k1]; }
      if (band == 7 && k2 == 0 && ln == 0) row[0] = Xr[0];   // DC bin -> band 7
      dif256_ip<1>(row, ln);   // barrier-free inverse, natural order out
    }
  }
  __syncthreads();
  size_t obase = (size_t)(sig * NB + band) * L;
  for (int idx = tid; idx < 4096; idx += 256) {
    int cc = idx & 15, n1 = idx >> 4;
    int k2e = k2base + cc;
    if (k2e < 625) {
      float s, c;
      __sincosf((TWO_PI / (float)L) * (float)(n1 * k2e), &s, &c);
      H[obase + (size_t)n1 * 625 + k2e] = cmulf(A[cc * 257 + n1], make_float2(c, s));
    }
  }
}

// ---------- I2: in-place DIF-625 (sign +), 2 waves/column, per-r sincos, energies ----------
__global__ __launch_bounds__(512) void i2_kernel(const float2* __restrict__ H,
                                                 float* __restrict__ E,
                                                 int sig0) {
  __shared__ float2 A[4 * 625];      // 20000 B
  __shared__ float P[2 * NHOPS];     // 1248 B
  int blk = blockIdx.x;
  int g = blk & 63, sb = blk >> 6;
  int band = sb & 7, sig = (sb >> 3) + sig0;
  int tid = threadIdx.x;
  int col = tid >> 7;                 // 4 columns, 2 waves (128 threads) each
  int j = tid & 127;                  // butterfly index within column, <125 active
  bool act = (j < 125);
  for (int idx = tid; idx < 2 * NHOPS; idx += 512) P[idx] = 0.0f;
  int n1 = 4 * g + col;
  const float2* Hc = H + (size_t)(sig * NB + band) * L + (size_t)n1 * 625;
  float2* a = A + col * 625;

  if (act) {  // stage 1: global -> LDS (stride 125, tw e^{+2pi i j r/625})
    float2 u[5];
#pragma unroll
    for (int r = 0; r < 5; ++r) u[r] = Hc[j + 125 * r];
    bf5s<1>(u);
    twapply<5>(u, (TWO_PI / 625.0f) * (float)j);
#pragma unroll
    for (int r = 0; r < 5; ++r) a[j + 125 * r] = u[r];
  }
  __syncthreads();
  if (act) {  // stage 2: stride 25, tw e^{+2pi i (j%25) r/125}
    int jm = j % 25, b1 = (j / 25) * 125 + jm;
    float2 u[5];
#pragma unroll
    for (int r = 0; r < 5; ++r) u[r] = a[b1 + 25 * r];
    bf5s<1>(u);
    twapply<5>(u, (TWO_PI / 125.0f) * (float)jm);
#pragma unroll
    for (int r = 0; r < 5; ++r) a[b1 + 25 * r] = u[r];
  }
  __syncthreads();
  if (act) {  // stage 3: stride 5, tw e^{+2pi i (j%5) r/25}
    int jm = j % 5, b1 = (j / 5) * 25 + jm;
    float2 u[5];
#pragma unroll
    for (int r = 0; r < 5; ++r) u[r] = a[b1 + 5 * r];
    bf5s<1>(u);
    twapply<5>(u, (TWO_PI / 25.0f) * (float)jm);
#pragma unroll
    for (int r = 0; r < 5; ++r) a[b1 + 5 * r] = u[r];
  }
  __syncthreads();
  if (act) {  // stage 4: no twiddle, scatter NATURAL n2 = 125 r + rev3(j)
    float2 u[5];
#pragma unroll
    for (int r = 0; r < 5; ++r) u[r] = a[5 * j + r];
    bf5s<1>(u);
    int rv = rev3_5(j);
#pragma unroll
    for (int r = 0; r < 5; ++r) a[125 * r + rv] = u[r];
  }
  __syncthreads();
  // energy: a[n2] = L*(w_band + i*o_band) at n = 256*n2 + n1; hop h sums n2 in [4h,4h+4)
  for (int t = tid; t < 4 * NHOPS; t += 512) {
    int c = t / NHOPS, h = t - c * NHOPS;
    const float2* S = A + c * 625 + 4 * h;
    float ex = 0.0f, ey = 0.0f;
#pragma unroll
    for (int d = 0; d < 4; ++d) {
      float2 z = S[d];
      ex += z.x * z.x;
      ey += z.y * z.y;
    }
    atomicAdd(&P[h], ex);
    atomicAdd(&P[NHOPS + h], ey);
  }
  __syncthreads();
  int eb = (sig * NB + band) * NHOPS;
  for (int idx = tid; idx < 2 * NHOPS; idx += 512) {
    int comp = idx / NHOPS, h = idx - comp * NHOPS;
    atomicAdd(&E[comp * (BATCH * NB * NHOPS) + eb + h], P[idx]);
  }
}

// ---------- finalize: loudness, diff, softmax-weighted sum (1/L^2 folded into SC) ----------
__global__ __launch_bounds__(1024) void finalize_kernel(const float* __restrict__ E,
                                                        float* __restrict__ out) {
  constexpr int ND = BATCH * NB * NCHUNK;  // 9920
  constexpr float SC = (1.0f / 2048.0f) / ((float)L * (float)L);
  __shared__ float diffs[ND];
  __shared__ float sred[1024];
  int tid = threadIdx.x;
  for (int idx = tid; idx < ND; idx += 1024) {
    int sb = idx / NCHUNK;
    int k = idx - sb * NCHUNK;
    float msw = (E[sb * NHOPS + k] + E[sb * NHOPS + k + 1]) * SC;
    float mso = (E[64 * NHOPS + sb * NHOPS + k] + E[64 * NHOPS + sb * NHOPS + k + 1]) * SC;
    float lw = -0.691f + 10.0f * log10f(msw + 1e-12f);
    float lo = -0.691f + 10.0f * log10f(mso + 1e-12f);
    diffs[idx] = lw - lo;
  }
  __syncthreads();
  float mx = -3.4e38f;
  for (int idx = tid; idx < ND; idx += 1024) mx = fmaxf(mx, diffs[idx]);
  sred[tid] = mx;
  __syncthreads();
  for (int s = 512; s > 0; s >>= 1) {
    if (tid < s) sred[tid] = fmaxf(sred[tid], sred[tid + s]);
    __syncthreads();
  }
  float gmax = sred[0];
  __syncthreads();
  float se = 0.0f, swd = 0.0f;
  for (int idx = tid; idx < ND; idx += 1024) {
    float d = diffs[idx];
    float e = expf(d - gmax);
    se += e;
    swd += d * e;
  }
  sred[tid] = se; __syncthreads();
  for (int s = 512; s > 0; s >>= 1) { if (tid < s) sred[tid] += sred[tid + s]; __syncthreads(); }
  float tot = sred[0];
  __syncthreads();
  sred[tid] = swd; __syncthreads();
  for (int s = 512; s > 0; s >>= 1) { if (tid < s) sred[tid] += sred[tid + s]; __syncthreads(); }
  if (tid == 0) out[0] = sred[0] / tot;
}

extern "C" void kernel_launch(void* const* d_in, const int* in_sizes, int n_in,
                              void* d_out, int out_size, void* d_ws, size_t ws_size,
                              hipStream_t stream) {
  (void)in_sizes; (void)n_in; (void)out_size; (void)ws_size;
  char* ws = (char*)d_ws;
  float2* G = (float2*)ws;                        // 10,240,000 B
  float2* X = (float2*)(ws + 10240000);           // 10,240,000 B
  float2* H = (float2*)(ws + 20480000);           // 81,920,000 B
  float*  E = (float*)(ws + 102400000);           // 79,872 B [2][64][156]
  const float* w = (const float*)d_in[0];
  const float* o = (const float*)d_in[1];

  f1_kernel<<<dim3(BATCH * 64), dim3(256), 0, stream>>>(w, o, G);
  f2_kernel<<<dim3(BATCH * 157), dim3(256), 0, stream>>>(G, X);
  i1_kernel<<<dim3(BATCH * NB * 40), dim3(256), 0, stream>>>(X, H);
  hipMemsetAsync(E, 0, 2 * BATCH * NB * NHOPS * sizeof(float), stream);
  i2_kernel<<<dim3(4 * NB * 64), dim3(512), 0, stream>>>(H, E, 0);
  i2_kernel<<<dim3(4 * NB * 64), dim3(512), 0, stream>>>(H, E, 4);
  finalize_kernel<<<dim3(1), dim3(1024), 0, stream>>>(E, (float*)d_out);
}